// Round 17
// baseline (502.197 us; speedup 1.0000x reference)
//
#include <hip/hip_runtime.h>
#include <hip/hip_bf16.h>

// StockFormer forward, MI355X — bf16 MFMA pipeline v10
// (padded-xh unconditional-load conv, 2048-block conv grid; rest = r16).
// B=4, S=256, N=128, F=64, D=E=128, NH=4, HD=32, BN=512, M=131072. Output f32.
typedef __attribute__((ext_vector_type(8))) short short8v;   // 8 bf16 (4 VGPR)
typedef __attribute__((ext_vector_type(4))) short short4v;   // 4 bf16 (2 VGPR)
typedef __attribute__((ext_vector_type(4))) float f32x4;
typedef __hip_bfloat16 bh;

constexpr long SF_ELEMS = 131072L * 128;   // elements per ws slot (bf16 -> 32 MiB)
#define MFMA16(a, b, c) __builtin_amdgcn_mfma_f32_16x16x32_bf16((a), (b), (c), 0, 0, 0)

__device__ __forceinline__ short bh_bits(float x) {
  bh h = __float2bfloat16(x);
  return *reinterpret_cast<short*>(&h);
}

// Arena (bf16 elems): 0 ta_w_in | 49152 ta_w_o | 65536 pl | 81920 ph | 98304 ac_w_in |
// 147456 ac_w_o | 163840 as_w_in | 212992 as_w_o | 229376 wrep | 278528 end. Then PE f32.

// ---------------------------------------------------------------------------
__global__ __launch_bounds__(256) void sf_wcvt(const float* __restrict__ s0, const float* __restrict__ s1,
                                               const float* __restrict__ s2, const float* __restrict__ s3,
                                               const float* __restrict__ s4, const float* __restrict__ s5,
                                               const float* __restrict__ s6, const float* __restrict__ s7,
                                               const float* __restrict__ cw,
                                               bh* __restrict__ dst) {
  int i = blockIdx.x * 256 + threadIdx.x;
  float v;
  if      (i <  49152) v = s0[i];
  else if (i <  65536) v = s1[i - 49152];
  else if (i <  81920) v = s2[i - 65536];
  else if (i <  98304) v = s3[i - 81920];
  else if (i < 147456) v = s4[i - 98304];
  else if (i < 163840) v = s5[i - 147456];
  else if (i < 212992) v = s6[i - 163840];
  else if (i < 229376) v = s7[i - 212992];
  else if (i < 278528) {                       // conv_w repack: wrep[tap][dch][ic]
    int j = i - 229376;
    int tap = j >> 14, rem = j & 16383;
    v = cw[rem * 3 + tap];
  } else return;
  dst[i] = __float2bfloat16(v);
}

// ---------------------------------------------------------------------------
__global__ __launch_bounds__(256) void sf_pe(float* __restrict__ pe) {
  int i = blockIdx.x * 256 + threadIdx.x;   // [0, 32768)
  int e = i & 127, s = i >> 7;
  int ii = e >> 1;
  float dv = expf(-0.0719557945041855f * (float)(2 * ii));
  float ang = (float)s * dv;
  pe[i] = (e & 1) ? cosf(ang) : sinf(ang);
}

// ---------------------------------------------------------------------------
// zero the 4 guard rows (0,1,258,259) of padded xh: [bnc][260][128]
// ---------------------------------------------------------------------------
__global__ __launch_bounds__(256) void sf_zguard(bh* __restrict__ xhp) {
  int i = blockIdx.x * 256 + threadIdx.x;     // [0, 262144)
  int bnc = i >> 9;
  int j = i & 511;
  int q = j >> 7;                              // 0..3
  int row = (q < 2) ? q : 256 + q;             // 0,1,258,259
  xhp[((long)bnc * 260 + row) * 128 + (j & 127)] = __float2bfloat16(0.f);
}

// ---------------------------------------------------------------------------
// z (xl_cat + PE, flat) and padded xh ([bnc][260][128], rows 2..257) in one pass.
// ---------------------------------------------------------------------------
__global__ __launch_bounds__(256) void sf_buildzx(const float* __restrict__ x,
                                                  const float* __restrict__ pe,
                                                  bh* __restrict__ z,
                                                  bh* __restrict__ xhp) {
  long i = (long)blockIdx.x * 256 + threadIdx.x;
  if (i >= SF_ELEMS) return;
  int e = (int)(i & 127);
  int s = (int)((i >> 7) & 255);
  int r = (int)(i >> 15);
  int b = r >> 7, stk = r & 127;
  float zv, hv;
  if (e < 64) {
    float val = x[(((long)b * 256 + s) * 128 + stk) * 64 + e];
    zv = val; hv = val;
  } else {
    int f = e - 64;
    int t2 = s >> 1;
    float a0 = x[(((long)b * 256 + 2 * t2) * 128 + stk) * 64 + f];
    float a1 = x[(((long)b * 256 + 2 * t2 + 1) * 128 + stk) * 64 + f];
    zv = 0.5f * (a0 + a1);
    float d = 0.5f * (a0 - a1);
    hv = (s & 1) ? -d : d;
  }
  z[i] = __float2bfloat16(zv + pe[s * 128 + e]);
  xhp[((long)r * 260 + s + 2) * 128 + e] = __float2bfloat16(hv);
}

// ---------------------------------------------------------------------------
// Fused-projection MFMA attention (r11-verbatim).
// ---------------------------------------------------------------------------
__global__ __launch_bounds__(256) void sf_attnp(const bh* Qsrc, const bh* KVsrc,
                                                const bh* __restrict__ Win,
                                                const float* __restrict__ bin,
                                                bh* __restrict__ O) {
  __shared__ bh Ks[256][36];      // 18.0 KB (krow, d)
  __shared__ bh Vt[32][260];      // 16.3 KB (d, krow)
  __shared__ bh QP[4][64][36];    // 18.0 KB per-wave: Q staging, then P tile
  const int t = threadIdx.x, lane = t & 63, w = t >> 6;
  const int lr = lane & 15, lg = lane >> 4;
  const int bn = blockIdx.x >> 2, h = blockIdx.x & 3;
  const long R0 = (long)bn * 256;
  const int ch = h * 32;
  const f32x4 z4 = {0.f, 0.f, 0.f, 0.f};
  const float SC2 = 0.2550351f;   // (1/sqrt(32)) * log2(e), folded into Q
  {
    short8v wq[2][4];
#pragma unroll
    for (int n = 0; n < 2; ++n)
#pragma unroll
      for (int ks = 0; ks < 4; ++ks)
        wq[n][ks] = *reinterpret_cast<const short8v*>(Win + (long)(ch + n * 16 + lr) * 128 + ks * 32 + lg * 8);
#pragma unroll
    for (int m2 = 0; m2 < 4; ++m2) {
      short8v asv[4];
#pragma unroll
      for (int ks = 0; ks < 4; ++ks)
        asv[ks] = *reinterpret_cast<const short8v*>(Qsrc + (R0 + w * 64 + m2 * 16 + lr) * 128 + ks * 32 + lg * 8);
#pragma unroll
      for (int n = 0; n < 2; ++n) {
        f32x4 acc = z4;
#pragma unroll
        for (int ks = 0; ks < 4; ++ks) acc = MFMA16(asv[ks], wq[n][ks], acc);
        float bb = bin[ch + n * 16 + lr];
#pragma unroll
        for (int r = 0; r < 4; ++r)
          QP[w][m2 * 16 + 4 * lg + r][n * 16 + lr] = __float2bfloat16((acc[r] + bb) * SC2);
      }
    }
  }
  {
    short8v wk[2][4], wv[2][4];
#pragma unroll
    for (int n = 0; n < 2; ++n)
#pragma unroll
      for (int ks = 0; ks < 4; ++ks) {
        wk[n][ks] = *reinterpret_cast<const short8v*>(Win + (long)(128 + ch + n * 16 + lr) * 128 + ks * 32 + lg * 8);
        wv[n][ks] = *reinterpret_cast<const short8v*>(Win + (long)(256 + ch + n * 16 + lr) * 128 + ks * 32 + lg * 8);
      }
#pragma unroll
    for (int m2 = 0; m2 < 4; ++m2) {
      short8v asv[4];
#pragma unroll
      for (int ks = 0; ks < 4; ++ks)
        asv[ks] = *reinterpret_cast<const short8v*>(KVsrc + (R0 + w * 64 + m2 * 16 + lr) * 128 + ks * 32 + lg * 8);
#pragma unroll
      for (int n = 0; n < 2; ++n) {
        f32x4 ak = z4, av = z4;
#pragma unroll
        for (int ks = 0; ks < 4; ++ks) {
          ak = MFMA16(asv[ks], wk[n][ks], ak);
          av = MFMA16(asv[ks], wv[n][ks], av);
        }
        float bk = bin[128 + ch + n * 16 + lr];
        float bv = bin[256 + ch + n * 16 + lr];
#pragma unroll
        for (int r = 0; r < 4; ++r)
          Ks[w * 64 + m2 * 16 + 4 * lg + r][n * 16 + lr] = __float2bfloat16(ak[r] + bk);
        short4v pv;
#pragma unroll
        for (int r = 0; r < 4; ++r) pv[r] = bh_bits(av[r] + bv);
        *reinterpret_cast<short4v*>(&Vt[n * 16 + lr][w * 64 + m2 * 16 + 4 * lg]) = pv;
      }
    }
  }
  __syncthreads();
  short8v aq[4];
#pragma unroll
  for (int mt = 0; mt < 4; ++mt)
    aq[mt] = *reinterpret_cast<const short8v*>(&QP[w][mt * 16 + lr][lg * 8]);
  bh* plp = &QP[w][0][0];   // P tile: (lr, c) at plp[lr*72 + c], wave-local
  f32x4 Oacc[4][2];
  float psum[4] = {0.f, 0.f, 0.f, 0.f};
#pragma unroll
  for (int mt = 0; mt < 4; ++mt) { Oacc[mt][0] = z4; Oacc[mt][1] = z4; }
#pragma unroll
  for (int kt = 0; kt < 4; ++kt) {
    short8v bvf[2][2];
#pragma unroll
    for (int dt = 0; dt < 2; ++dt)
#pragma unroll
      for (int ks = 0; ks < 2; ++ks)
        bvf[dt][ks] = *reinterpret_cast<const short8v*>(&Vt[dt * 16 + lr][kt * 64 + ks * 32 + lg * 8]);
#pragma unroll
    for (int mt = 0; mt < 4; ++mt) {
      f32x4 st[4];
#pragma unroll
      for (int nt = 0; nt < 4; ++nt) {
        short8v bk = *reinterpret_cast<const short8v*>(&Ks[kt * 64 + nt * 16 + lr][lg * 8]);
        st[nt] = MFMA16(bk, aq[mt], z4);     // S^T·SC2 = K·(Q*SC2)^T
      }
      float ps = 0.f;
#pragma unroll
      for (int nt = 0; nt < 4; ++nt) {
        float p0 = exp2f(st[nt][0]);
        float p1 = exp2f(st[nt][1]);
        float p2 = exp2f(st[nt][2]);
        float p3 = exp2f(st[nt][3]);
        ps += (p0 + p1) + (p2 + p3);
        short4v pk;
        pk[0] = bh_bits(p0); pk[1] = bh_bits(p1); pk[2] = bh_bits(p2); pk[3] = bh_bits(p3);
        *reinterpret_cast<short4v*>(&plp[lr * 72 + nt * 16 + 4 * lg]) = pk;
      }
      psum[mt] += ps;
#pragma unroll
      for (int ks = 0; ks < 2; ++ks) {
        short8v ap = *reinterpret_cast<const short8v*>(&plp[lr * 72 + ks * 32 + lg * 8]);
        Oacc[mt][0] = MFMA16(ap, bvf[0][ks], Oacc[mt][0]);
        Oacc[mt][1] = MFMA16(ap, bvf[1][ks], Oacc[mt][1]);
      }
    }
  }
#pragma unroll
  for (int mt = 0; mt < 4; ++mt) {
    float ps = psum[mt];
    ps += __shfl_xor(ps, 16, 64);
    ps += __shfl_xor(ps, 32, 64);
    float inv = 1.f / ps;
#pragma unroll
    for (int r = 0; r < 4; ++r) {
      float invr = __shfl(inv, 4 * lg + r, 64);
      long row = R0 + w * 64 + mt * 16 + 4 * lg + r;
      O[row * 128 + ch + lr]      = __float2bfloat16(Oacc[mt][0][r] * invr);
      O[row * 128 + ch + 16 + lr] = __float2bfloat16(Oacc[mt][1][r] * invr);
    }
  }
}

// ---------------------------------------------------------------------------
// conv v10: padded xh (no branches), 2048 blocks = (bnc, quarter of 64 sc),
// 4 waves x 16 sc; A-frags hoisted; chained k_h GEMM; wide stores.
// ---------------------------------------------------------------------------
__global__ __launch_bounds__(256) void sf_convkh(const bh* __restrict__ Xhp,
                                                 const bh* __restrict__ Wr,
                                                 const float* __restrict__ cbias,
                                                 const bh* __restrict__ Wph,
                                                 const float* __restrict__ bph,
                                                 bh* __restrict__ KH) {
  __shared__ bh Lw[4][16][140];   // 17.9 KB
  const int t = threadIdx.x, lane = t & 63, w = t >> 6;
  const int lr = lane & 15, lg = lane >> 4;
  const int bnc = blockIdx.x >> 2;
  const int quarter = blockIdx.x & 3;
  const int b = bnc >> 7, stk = bnc & 127;
  const int R0 = quarter * 64 + w * 16;
  const f32x4 z4 = {0.f, 0.f, 0.f, 0.f};
  // hoisted unconditional A-loads: padded row = R0 + lr + 2*tap  (>=0, <260)
  short8v a[3][4];
#pragma unroll
  for (int tap = 0; tap < 3; ++tap)
#pragma unroll
    for (int ks = 0; ks < 4; ++ks)
      a[tap][ks] = *reinterpret_cast<const short8v*>(
          Xhp + ((long)bnc * 260 + R0 + lr + 2 * tap) * 128 + ks * 32 + lg * 8);
  f32x4 acc[8];
#pragma unroll
  for (int n = 0; n < 8; ++n) acc[n] = z4;
#pragma unroll
  for (int ks = 0; ks < 4; ++ks)
#pragma unroll
    for (int tap = 0; tap < 3; ++tap)
#pragma unroll
      for (int n = 0; n < 8; ++n) {
        short8v bb = *reinterpret_cast<const short8v*>(
            Wr + (long)tap * 16384 + (long)(n * 16 + lr) * 128 + ks * 32 + lg * 8);
        acc[n] = MFMA16(a[tap][ks], bb, acc[n]);
      }
#pragma unroll
  for (int n = 0; n < 8; ++n) {
    float bv = cbias[n * 16 + lr];
#pragma unroll
    for (int r = 0; r < 4; ++r)
      Lw[w][4 * lg + r][n * 16 + lr] = __float2bfloat16(fmaxf(acc[n][r] + bv, 0.f));
  }
  // chained k_h = y_h · Wph^T + bph (per-wave 16-row tile, in-order DS)
  {
    short8v a2[4];
#pragma unroll
    for (int ks = 0; ks < 4; ++ks)
      a2[ks] = *reinterpret_cast<const short8v*>(&Lw[w][lr][ks * 32 + lg * 8]);
    f32x4 ac2[8];
#pragma unroll
    for (int n = 0; n < 8; ++n) ac2[n] = z4;
#pragma unroll
    for (int ks = 0; ks < 4; ++ks)
#pragma unroll
      for (int n = 0; n < 8; ++n) {
        short8v b2 = *reinterpret_cast<const short8v*>(
            Wph + (long)(n * 16 + lr) * 128 + ks * 32 + lg * 8);
        ac2[n] = MFMA16(a2[ks], b2, ac2[n]);
      }
#pragma unroll
    for (int n = 0; n < 8; ++n) {
      float bv = bph[n * 16 + lr];
#pragma unroll
      for (int r = 0; r < 4; ++r)
        Lw[w][4 * lg + r][n * 16 + lr] = __float2bfloat16(ac2[n][r] + bv);
    }
  }
#pragma unroll
  for (int c = 0; c < 4; ++c) {
    int row_l = c * 4 + lg;
    int sc = R0 + row_l;
    int rp = b * 128 + (sc >> 1);
    int sp = ((sc & 1) << 7) + stk;
    short8v v = *reinterpret_cast<const short8v*>(&Lw[w][row_l][lr * 8]);
    *reinterpret_cast<short8v*>(KH + ((long)rp * 256 + sp) * 128 + lr * 8) = v;
  }
}

// ---------------------------------------------------------------------------
// Fused decoder chain (r16-verbatim): X -> y_l -> q_l [stored] -> y_l2 -> heads.
// ---------------------------------------------------------------------------
__global__ __launch_bounds__(256) void sf_encdec(const bh* __restrict__ X,
                                                 const bh* __restrict__ Wo, const float* __restrict__ bo,
                                                 const bh* __restrict__ Wpl, const float* __restrict__ bpl,
                                                 const float* __restrict__ rw, const float* __restrict__ rb,
                                                 const float* __restrict__ cw, const float* __restrict__ cb,
                                                 bh* __restrict__ Yq, float* __restrict__ out,
                                                 long off_reg, long off_cla) {
  __shared__ bh Lw[4][32][140];
  __shared__ float hw[3][128];
  const int t = threadIdx.x, lane = t & 63, w = t >> 6;
  const int lr = lane & 15, lg = lane >> 4;
  const long R0 = (long)blockIdx.x * 128 + w * 32;
  const f32x4 z4 = {0.f, 0.f, 0.f, 0.f};
  if (t < 128) { hw[0][t] = rw[t]; hw[1][t] = cw[t]; hw[2][t] = cw[128 + t]; }
  {
    short8v a[2][4];
#pragma unroll
    for (int ks = 0; ks < 4; ++ks) {
      a[0][ks] = *reinterpret_cast<const short8v*>(X + (R0 + lr) * 128 + ks * 32 + lg * 8);
      a[1][ks] = *reinterpret_cast<const short8v*>(X + (R0 + 16 + lr) * 128 + ks * 32 + lg * 8);
    }
    f32x4 acc[2][8];
#pragma unroll
    for (int m = 0; m < 2; ++m)
#pragma unroll
      for (int n = 0; n < 8; ++n) acc[m][n] = z4;
#pragma unroll
    for (int ks = 0; ks < 4; ++ks)
#pragma unroll
      for (int n = 0; n < 8; ++n) {
        short8v b = *reinterpret_cast<const short8v*>(Wo + (long)(n * 16 + lr) * 128 + ks * 32 + lg * 8);
        acc[0][n] = MFMA16(a[0][ks], b, acc[0][n]);
        acc[1][n] = MFMA16(a[1][ks], b, acc[1][n]);
      }
#pragma unroll
    for (int n = 0; n < 8; ++n) {
      float bv = bo[n * 16 + lr];
#pragma unroll
      for (int m = 0; m < 2; ++m)
#pragma unroll
        for (int r = 0; r < 4; ++r)
          Lw[w][m * 16 + 4 * lg + r][n * 16 + lr] = __float2bfloat16(acc[m][n][r] + bv);
    }
  }
#pragma unroll
  for (int stage = 0; stage < 2; ++stage) {
    short8v a[2][4];
#pragma unroll
    for (int ks = 0; ks < 4; ++ks) {
      a[0][ks] = *reinterpret_cast<const short8v*>(&Lw[w][lr][ks * 32 + lg * 8]);
      a[1][ks] = *reinterpret_cast<const short8v*>(&Lw[w][16 + lr][ks * 32 + lg * 8]);
    }
    f32x4 acc[2][8];
#pragma unroll
    for (int m = 0; m < 2; ++m)
#pragma unroll
      for (int n = 0; n < 8; ++n) acc[m][n] = z4;
#pragma unroll
    for (int ks = 0; ks < 4; ++ks)
#pragma unroll
      for (int n = 0; n < 8; ++n) {
        short8v b = *reinterpret_cast<const short8v*>(Wpl + (long)(n * 16 + lr) * 128 + ks * 32 + lg * 8);
        acc[0][n] = MFMA16(a[0][ks], b, acc[0][n]);
        acc[1][n] = MFMA16(a[1][ks], b, acc[1][n]);
      }
#pragma unroll
    for (int n = 0; n < 8; ++n) {
      float bv = bpl[n * 16 + lr];
#pragma unroll
      for (int m = 0; m < 2; ++m)
#pragma unroll
        for (int r = 0; r < 4; ++r)
          Lw[w][m * 16 + 4 * lg + r][n * 16 + lr] = __float2bfloat16(acc[m][n][r] + bv);
    }
    if (stage == 0) {
#pragma unroll
      for (int c = 0; c < 8; ++c) {
        int row_l = c * 4 + lg;
        short8v v = *reinterpret_cast<const short8v*>(&Lw[w][row_l][lr * 8]);
        *reinterpret_cast<short8v*>(Yq + (R0 + row_l) * 128 + lr * 8) = v;
      }
    }
  }
  __syncthreads();
  {
    const int rr = lane >> 1, hh = lane & 1;
    float d0 = 0.f, d1 = 0.f, d2 = 0.f;
#pragma unroll
    for (int j = 0; j < 8; ++j) {
      short8v v8 = *reinterpret_cast<const short8v*>(&Lw[w][rr][hh * 64 + j * 8]);
      const bh* vv = reinterpret_cast<const bh*>(&v8);
#pragma unroll
      for (int k = 0; k < 8; ++k) {
        float f = __bfloat162float(vv[k]);
        int c = hh * 64 + j * 8 + k;
        d0 = fmaf(f, hw[0][c], d0);
        d1 = fmaf(f, hw[1][c], d1);
        d2 = fmaf(f, hw[2][c], d2);
      }
    }
    d0 += __shfl_xor(d0, 1, 64);
    d1 += __shfl_xor(d1, 1, 64);
    d2 += __shfl_xor(d2, 1, 64);
    if (hh == 0) {
      long row = R0 + rr;
      d0 += rb[0]; d1 += cb[0]; d2 += cb[1];
      float mx = fmaxf(d1, d2);
      float e1 = __expf(d1 - mx), e2 = __expf(d2 - mx);
      float inv = 1.f / (e1 + e2);
      out[off_reg + row] = d0;
      out[off_cla + row * 2] = e1 * inv;
      out[off_cla + row * 2 + 1] = e2 * inv;
    }
  }
}

// ---------------------------------------------------------------------------
// Final (r16-verbatim): fused = self·Was + cross·Wac + biases (f32) -> heads.
// ---------------------------------------------------------------------------
__global__ __launch_bounds__(256) void sf_fin2(const bh* __restrict__ Xs,
                                               const bh* __restrict__ Was, const float* __restrict__ bs,
                                               const bh* __restrict__ Xc,
                                               const bh* __restrict__ Wac, const float* __restrict__ bc,
                                               const float* __restrict__ rw, const float* __restrict__ rb,
                                               const float* __restrict__ cw, const float* __restrict__ cb,
                                               float* __restrict__ out, long off_reg, long off_cla) {
  __shared__ bh Lw[4][32][140];
  __shared__ float hw[3][128];
  const int t = threadIdx.x, lane = t & 63, w = t >> 6;
  const int lr = lane & 15, lg = lane >> 4;
  const long R0 = (long)blockIdx.x * 128 + w * 32;
  const f32x4 z4 = {0.f, 0.f, 0.f, 0.f};
  if (t < 128) { hw[0][t] = rw[t]; hw[1][t] = cw[t]; hw[2][t] = cw[128 + t]; }
  {
    f32x4 acc[2][8];
#pragma unroll
    for (int m = 0; m < 2; ++m)
#pragma unroll
      for (int n = 0; n < 8; ++n) acc[m][n] = z4;
    {
      short8v a[2][4];
#pragma unroll
      for (int ks = 0; ks < 4; ++ks) {
        a[0][ks] = *reinterpret_cast<const short8v*>(Xs + (R0 + lr) * 128 + ks * 32 + lg * 8);
        a[1][ks] = *reinterpret_cast<const short8v*>(Xs + (R0 + 16 + lr) * 128 + ks * 32 + lg * 8);
      }
#pragma unroll
      for (int ks = 0; ks < 4; ++ks)
#pragma unroll
        for (int n = 0; n < 8; ++n) {
          short8v b = *reinterpret_cast<const short8v*>(Was + (long)(n * 16 + lr) * 128 + ks * 32 + lg * 8);
          acc[0][n] = MFMA16(a[0][ks], b, acc[0][n]);
          acc[1][n] = MFMA16(a[1][ks], b, acc[1][n]);
        }
    }
    {
      short8v a[2][4];
#pragma unroll
      for (int ks = 0; ks < 4; ++ks) {
        a[0][ks] = *reinterpret_cast<const short8v*>(Xc + (R0 + lr) * 128 + ks * 32 + lg * 8);
        a[1][ks] = *reinterpret_cast<const short8v*>(Xc + (R0 + 16 + lr) * 128 + ks * 32 + lg * 8);
      }
#pragma unroll
      for (int ks = 0; ks < 4; ++ks)
#pragma unroll
        for (int n = 0; n < 8; ++n) {
          short8v b = *reinterpret_cast<const short8v*>(Wac + (long)(n * 16 + lr) * 128 + ks * 32 + lg * 8);
          acc[0][n] = MFMA16(a[0][ks], b, acc[0][n]);
          acc[1][n] = MFMA16(a[1][ks], b, acc[1][n]);
        }
    }
#pragma unroll
    for (int n = 0; n < 8; ++n) {
      float bv = bs[n * 16 + lr] + bc[n * 16 + lr];
#pragma unroll
      for (int m = 0; m < 2; ++m)
#pragma unroll
        for (int r = 0; r < 4; ++r)
          Lw[w][m * 16 + 4 * lg + r][n * 16 + lr] = __float2bfloat16(acc[m][n][r] + bv);
    }
  }
  __syncthreads();
  {
    const int rr = lane >> 1, hh = lane & 1;
    float d0 = 0.f, d1 = 0.f, d2 = 0.f;
#pragma unroll
    for (int j = 0; j < 8; ++j) {
      short8v v8 = *reinterpret_cast<const short8v*>(&Lw[w][rr][hh * 64 + j * 8]);
      const bh* vv = reinterpret_cast<const bh*>(&v8);
#pragma unroll
      for (int k = 0; k < 8; ++k) {
        float f = __bfloat162float(vv[k]);
        int c = hh * 64 + j * 8 + k;
        d0 = fmaf(f, hw[0][c], d0);
        d1 = fmaf(f, hw[1][c], d1);
        d2 = fmaf(f, hw[2][c], d2);
      }
    }
    d0 += __shfl_xor(d0, 1, 64);
    d1 += __shfl_xor(d1, 1, 64);
    d2 += __shfl_xor(d2, 1, 64);
    if (hh == 0) {
      long row = R0 + rr;
      d0 += rb[0]; d1 += cb[0]; d2 += cb[1];
      float mx = fmaxf(d1, d2);
      float e1 = __expf(d1 - mx), e2 = __expf(d2 - mx);
      float inv = 1.f / (e1 + e2);
      out[off_reg + row] = d0;
      out[off_cla + row * 2] = e1 * inv;
      out[off_cla + row * 2 + 1] = e2 * inv;
    }
  }
}

// ---------------------------------------------------------------------------
extern "C" void kernel_launch(void* const* d_in, const int* in_sizes, int n_in,
                              void* d_out, int out_size, void* d_ws, size_t ws_size,
                              hipStream_t stream) {
  (void)in_sizes; (void)n_in; (void)out_size; (void)ws_size;
  const float* x       = (const float*)d_in[0];
  const float* ta_w_in = (const float*)d_in[2];
  const float* ta_b_in = (const float*)d_in[3];
  const float* ta_w_o  = (const float*)d_in[4];
  const float* ta_b_o  = (const float*)d_in[5];
  const float* conv_w  = (const float*)d_in[6];
  const float* conv_b  = (const float*)d_in[7];
  const float* pl_w    = (const float*)d_in[8];
  const float* pl_b    = (const float*)d_in[9];
  const float* ph_w    = (const float*)d_in[10];
  const float* ph_b    = (const float*)d_in[11];
  const float* as_w_in = (const float*)d_in[12];
  const float* as_b_in = (const float*)d_in[13];
  const float* as_w_o  = (const float*)d_in[14];
  const float* as_b_o  = (const float*)d_in[15];
  const float* ac_w_in = (const float*)d_in[16];
  const float* ac_b_in = (const float*)d_in[17];
  const float* ac_w_o  = (const float*)d_in[18];
  const float* ac_b_o  = (const float*)d_in[19];
  const float* rl_w    = (const float*)d_in[20];
  const float* rl_b    = (const float*)d_in[21];
  const float* cl_w    = (const float*)d_in[22];
  const float* cl_b    = (const float*)d_in[23];
  const float* rf_w    = (const float*)d_in[24];
  const float* rf_b    = (const float*)d_in[25];
  const float* cf_w    = (const float*)d_in[26];
  const float* cf_b    = (const float*)d_in[27];
  float* out = (float*)d_out;

  bh* S0 = (bh*)d_ws;
  bh* S1 = S0 + SF_ELEMS;
  bh* S2 = S1 + SF_ELEMS;
  bh* S3 = S2 + SF_ELEMS;             // xhp lives here (extends into S4 space)
  bh* S4 = S3 + SF_ELEMS;
  bh* A  = S4 + SF_ELEMS;             // bf16 arena (278528)
  float* PE = (float*)(A + 278528);   // 32768 f32

  dim3 blk(256);
  const int GZ = (int)(SF_ELEMS / 256);
  const int GL = 1024;                // 131072 / 128

  sf_wcvt<<<1088, blk, 0, stream>>>(ta_w_in, ta_w_o, pl_w, ph_w, ac_w_in, ac_w_o,
                                    as_w_in, as_w_o, conv_w, A);
  sf_pe<<<128, blk, 0, stream>>>(PE);
  sf_zguard<<<1024, blk, 0, stream>>>(S3);

  // ---- encoder ----
  sf_buildzx<<<GZ, blk, 0, stream>>>(x, PE, S0, S3);                           // S0 = z, S3 = xhp
  sf_attnp<<<2048, blk, 0, stream>>>(S0, S0, A, ta_b_in, S1);                  // S1 = enc attn
  sf_encdec<<<GL, blk, 0, stream>>>(S1, A + 49152, ta_b_o, A + 65536, pl_b,
                                    rl_w, rl_b, cl_w, cl_b, S2, out,
                                    393216L, 524288L);                         // S2 = q_l + lreg/lcla
  sf_convkh<<<2048, blk, 0, stream>>>(S3, A + 229376, conv_b, A + 81920, ph_b, S0); // S0 = k_h

  // ---- cross attention (q = q_l, k/v = k_h) ----
  sf_attnp<<<2048, blk, 0, stream>>>(S2, S0, A + 98304, ac_b_in, S3);          // S3 = cross attn

  // ---- self attention (q/k/v = q_l) ----
  sf_attnp<<<2048, blk, 0, stream>>>(S2, S2, A + 163840, as_b_in, S1);         // S1 = self attn

  // ---- fused out-projections + heads ----
  sf_fin2<<<GL, blk, 0, stream>>>(S1, A + 212992, as_b_o, S3, A + 147456, ac_b_o,
                                  rf_w, rf_b, cf_w, cf_b, out, 0L, 131072L);   // reg/cla
}

// Round 18
// 451.630 us; speedup vs baseline: 1.1120x; 1.1120x over previous
//
#include <hip/hip_runtime.h>
#include <hip/hip_bf16.h>

// StockFormer forward, MI355X — bf16 MFMA pipeline v11
// (weight folding: q_l/k_h eliminated; conv reverted to r16 form minus ph chain).
// B=4, S=256, N=128, F=64, D=E=128, NH=4, HD=32, BN=512, M=131072. Output f32.
typedef __attribute__((ext_vector_type(8))) short short8v;   // 8 bf16 (4 VGPR)
typedef __attribute__((ext_vector_type(4))) short short4v;   // 4 bf16 (2 VGPR)
typedef __attribute__((ext_vector_type(4))) float f32x4;
typedef __hip_bfloat16 bh;

constexpr long SF_ELEMS = 131072L * 128;   // elements per ws slot (bf16 -> 32 MiB)
#define MFMA16(a, b, c) __builtin_amdgcn_mfma_f32_16x16x32_bf16((a), (b), (c), 0, 0, 0)

__device__ __forceinline__ short bh_bits(float x) {
  bh h = __float2bfloat16(x);
  return *reinterpret_cast<short*>(&h);
}

// Arena (bf16 elems):
// 0 ta_w_in | 49152 ta_w_o | 65536 pl | 81920 ph | 98304 ac_w_in | 147456 ac_w_o |
// 163840 as_w_in | 212992 as_w_o | 229376 wrep | 278528 plT | 294912 phT |
// 311296 asF(3x16384) | 360448 acqF | 376832 ackF | 393216 acvF | 409600 pl2 | end 425984.
// Then PE (32768 f32), then FB (896 f32 folded biases: [0:384) asF | [384:768) acF | [768:896) pl2F).

// ---------------------------------------------------------------------------
__global__ __launch_bounds__(256) void sf_wcvt(const float* __restrict__ s0, const float* __restrict__ s1,
                                               const float* __restrict__ s2, const float* __restrict__ s3,
                                               const float* __restrict__ s4, const float* __restrict__ s5,
                                               const float* __restrict__ s6, const float* __restrict__ s7,
                                               const float* __restrict__ cw,
                                               bh* __restrict__ dst) {
  int i = blockIdx.x * 256 + threadIdx.x;
  float v;
  if      (i <  49152) v = s0[i];
  else if (i <  65536) v = s1[i - 49152];
  else if (i <  81920) v = s2[i - 65536];
  else if (i <  98304) v = s3[i - 81920];
  else if (i < 147456) v = s4[i - 98304];
  else if (i < 163840) v = s5[i - 147456];
  else if (i < 212992) v = s6[i - 163840];
  else if (i < 229376) v = s7[i - 212992];
  else if (i < 278528) {                       // conv_w repack: wrep[tap][dch][ic]
    int j = i - 229376;
    int tap = j >> 14, rem = j & 16383;
    v = cw[rem * 3 + tap];
  } else if (i < 294912) {                     // plT[r][c] = pl[c][r]
    int j = i - 278528;
    v = s2[(j & 127) * 128 + (j >> 7)];
  } else if (i < 311296) {                     // phT[r][c] = ph[c][r]
    int j = i - 294912;
    v = s3[(j & 127) * 128 + (j >> 7)];
  } else return;
  dst[i] = __float2bfloat16(v);
}

// ---------------------------------------------------------------------------
__global__ __launch_bounds__(256) void sf_pe(float* __restrict__ pe) {
  int i = blockIdx.x * 256 + threadIdx.x;   // [0, 32768)
  int e = i & 127, s = i >> 7;
  int ii = e >> 1;
  float dv = expf(-0.0719557945041855f * (float)(2 * ii));
  float ang = (float)s * dv;
  pe[i] = (e & 1) ? cosf(ang) : sinf(ang);
}

// ---------------------------------------------------------------------------
// Weight fold: out = X(128 rows) · B^T-convention GEMM (Y[i][j]=sum X[i][k]*B[j][k]).
// 7 blocks select (X, B, out) segments. No bias. Wide bf16 stores via LDS.
// ---------------------------------------------------------------------------
__global__ __launch_bounds__(256) void sf_foldw(const bh* __restrict__ A0) {
  __shared__ bh Lw[4][32][140];
  const int t = threadIdx.x, lane = t & 63, w = t >> 6;
  const int lr = lane & 15, lg = lane >> 4;
  const f32x4 z4 = {0.f, 0.f, 0.f, 0.f};
  const bh* Xp; const bh* Bp; bh* Op;
  int blk = blockIdx.x;
  bh* A = const_cast<bh*>(A0);
  if (blk < 3)      { Xp = A0 + 163840 + blk * 16384; Bp = A0 + 278528; Op = A + 311296 + blk * 16384; }
  else if (blk == 3){ Xp = A0 + 98304;                Bp = A0 + 278528; Op = A + 360448; }
  else if (blk == 4){ Xp = A0 + 98304 + 16384;        Bp = A0 + 294912; Op = A + 376832; }
  else if (blk == 5){ Xp = A0 + 98304 + 32768;        Bp = A0 + 294912; Op = A + 393216; }
  else              { Xp = A0 + 65536;                Bp = A0 + 278528; Op = A + 409600; }
  const long R0 = (long)w * 32;
  short8v a[2][4];
#pragma unroll
  for (int ks = 0; ks < 4; ++ks) {
    a[0][ks] = *reinterpret_cast<const short8v*>(Xp + (R0 + lr) * 128 + ks * 32 + lg * 8);
    a[1][ks] = *reinterpret_cast<const short8v*>(Xp + (R0 + 16 + lr) * 128 + ks * 32 + lg * 8);
  }
  f32x4 acc[2][8];
#pragma unroll
  for (int m = 0; m < 2; ++m)
#pragma unroll
    for (int n = 0; n < 8; ++n) acc[m][n] = z4;
#pragma unroll
  for (int ks = 0; ks < 4; ++ks)
#pragma unroll
    for (int n = 0; n < 8; ++n) {
      short8v b = *reinterpret_cast<const short8v*>(Bp + (long)(n * 16 + lr) * 128 + ks * 32 + lg * 8);
      acc[0][n] = MFMA16(a[0][ks], b, acc[0][n]);
      acc[1][n] = MFMA16(a[1][ks], b, acc[1][n]);
    }
#pragma unroll
  for (int n = 0; n < 8; ++n)
#pragma unroll
    for (int m = 0; m < 2; ++m)
#pragma unroll
      for (int r = 0; r < 4; ++r)
        Lw[w][m * 16 + 4 * lg + r][n * 16 + lr] = __float2bfloat16(acc[m][n][r]);
#pragma unroll
  for (int c = 0; c < 8; ++c) {
    int row_l = c * 4 + lg;
    short8v v = *reinterpret_cast<const short8v*>(&Lw[w][row_l][lr * 8]);
    *reinterpret_cast<short8v*>(Op + (R0 + row_l) * 128 + lr * 8) = v;
  }
}

// ---------------------------------------------------------------------------
// Bias fold (f32): FB[i] = dot(W1row_i, b2) + b1_i for the 5 folded segments.
// ---------------------------------------------------------------------------
__global__ __launch_bounds__(256) void sf_foldb(const float* __restrict__ as_w, const float* __restrict__ as_b,
                                                const float* __restrict__ ac_w, const float* __restrict__ ac_b,
                                                const float* __restrict__ pl_w, const float* __restrict__ pl_b,
                                                const float* __restrict__ ph_b,
                                                float* __restrict__ FB) {
  int i = blockIdx.x * 256 + threadIdx.x;
  if (i >= 896) return;
  const float* w1; const float* b2; float b1;
  if (i < 384)      { w1 = as_w + (long)i * 128;           b2 = pl_b; b1 = as_b[i]; }
  else if (i < 512) { w1 = ac_w + (long)(i - 384) * 128;   b2 = pl_b; b1 = ac_b[i - 384]; }
  else if (i < 640) { w1 = ac_w + (long)(i - 512 + 128) * 128; b2 = ph_b; b1 = ac_b[i - 512 + 128]; }
  else if (i < 768) { w1 = ac_w + (long)(i - 640 + 256) * 128; b2 = ph_b; b1 = ac_b[i - 640 + 256]; }
  else              { w1 = pl_w + (long)(i - 768) * 128;   b2 = pl_b; b1 = pl_b[i - 768]; }
  float d = b1;
  for (int k = 0; k < 128; ++k) d = fmaf(w1[k], b2[k], d);
  FB[i] = d;
}

// ---------------------------------------------------------------------------
// z (xl_cat + PE) and xh (xh_cat) in one pass over x.
// ---------------------------------------------------------------------------
__global__ __launch_bounds__(256) void sf_buildzx(const float* __restrict__ x,
                                                  const float* __restrict__ pe,
                                                  bh* __restrict__ z,
                                                  bh* __restrict__ xh) {
  long i = (long)blockIdx.x * 256 + threadIdx.x;
  if (i >= SF_ELEMS) return;
  int e = (int)(i & 127);
  int s = (int)((i >> 7) & 255);
  int r = (int)(i >> 15);
  int b = r >> 7, stk = r & 127;
  float zv, hv;
  if (e < 64) {
    float val = x[(((long)b * 256 + s) * 128 + stk) * 64 + e];
    zv = val; hv = val;
  } else {
    int f = e - 64;
    int t2 = s >> 1;
    float a0 = x[(((long)b * 256 + 2 * t2) * 128 + stk) * 64 + f];
    float a1 = x[(((long)b * 256 + 2 * t2 + 1) * 128 + stk) * 64 + f];
    zv = 0.5f * (a0 + a1);
    float d = 0.5f * (a0 - a1);
    hv = (s & 1) ? -d : d;
  }
  z[i] = __float2bfloat16(zv + pe[s * 128 + e]);
  xh[i] = __float2bfloat16(hv);
}

// ---------------------------------------------------------------------------
// Fused-projection MFMA attention (r11-verbatim).
// ---------------------------------------------------------------------------
__global__ __launch_bounds__(256) void sf_attnp(const bh* Qsrc, const bh* KVsrc,
                                                const bh* __restrict__ Win,
                                                const float* __restrict__ bin,
                                                bh* __restrict__ O) {
  __shared__ bh Ks[256][36];
  __shared__ bh Vt[32][260];
  __shared__ bh QP[4][64][36];
  const int t = threadIdx.x, lane = t & 63, w = t >> 6;
  const int lr = lane & 15, lg = lane >> 4;
  const int bn = blockIdx.x >> 2, h = blockIdx.x & 3;
  const long R0 = (long)bn * 256;
  const int ch = h * 32;
  const f32x4 z4 = {0.f, 0.f, 0.f, 0.f};
  const float SC2 = 0.2550351f;   // (1/sqrt(32)) * log2(e)
  {
    short8v wq[2][4];
#pragma unroll
    for (int n = 0; n < 2; ++n)
#pragma unroll
      for (int ks = 0; ks < 4; ++ks)
        wq[n][ks] = *reinterpret_cast<const short8v*>(Win + (long)(ch + n * 16 + lr) * 128 + ks * 32 + lg * 8);
#pragma unroll
    for (int m2 = 0; m2 < 4; ++m2) {
      short8v asv[4];
#pragma unroll
      for (int ks = 0; ks < 4; ++ks)
        asv[ks] = *reinterpret_cast<const short8v*>(Qsrc + (R0 + w * 64 + m2 * 16 + lr) * 128 + ks * 32 + lg * 8);
#pragma unroll
      for (int n = 0; n < 2; ++n) {
        f32x4 acc = z4;
#pragma unroll
        for (int ks = 0; ks < 4; ++ks) acc = MFMA16(asv[ks], wq[n][ks], acc);
        float bb = bin[ch + n * 16 + lr];
#pragma unroll
        for (int r = 0; r < 4; ++r)
          QP[w][m2 * 16 + 4 * lg + r][n * 16 + lr] = __float2bfloat16((acc[r] + bb) * SC2);
      }
    }
  }
  {
    short8v wk[2][4], wv[2][4];
#pragma unroll
    for (int n = 0; n < 2; ++n)
#pragma unroll
      for (int ks = 0; ks < 4; ++ks) {
        wk[n][ks] = *reinterpret_cast<const short8v*>(Win + (long)(128 + ch + n * 16 + lr) * 128 + ks * 32 + lg * 8);
        wv[n][ks] = *reinterpret_cast<const short8v*>(Win + (long)(256 + ch + n * 16 + lr) * 128 + ks * 32 + lg * 8);
      }
#pragma unroll
    for (int m2 = 0; m2 < 4; ++m2) {
      short8v asv[4];
#pragma unroll
      for (int ks = 0; ks < 4; ++ks)
        asv[ks] = *reinterpret_cast<const short8v*>(KVsrc + (R0 + w * 64 + m2 * 16 + lr) * 128 + ks * 32 + lg * 8);
#pragma unroll
      for (int n = 0; n < 2; ++n) {
        f32x4 ak = z4, av = z4;
#pragma unroll
        for (int ks = 0; ks < 4; ++ks) {
          ak = MFMA16(asv[ks], wk[n][ks], ak);
          av = MFMA16(asv[ks], wv[n][ks], av);
        }
        float bk = bin[128 + ch + n * 16 + lr];
        float bv = bin[256 + ch + n * 16 + lr];
#pragma unroll
        for (int r = 0; r < 4; ++r)
          Ks[w * 64 + m2 * 16 + 4 * lg + r][n * 16 + lr] = __float2bfloat16(ak[r] + bk);
        short4v pv;
#pragma unroll
        for (int r = 0; r < 4; ++r) pv[r] = bh_bits(av[r] + bv);
        *reinterpret_cast<short4v*>(&Vt[n * 16 + lr][w * 64 + m2 * 16 + 4 * lg]) = pv;
      }
    }
  }
  __syncthreads();
  short8v aq[4];
#pragma unroll
  for (int mt = 0; mt < 4; ++mt)
    aq[mt] = *reinterpret_cast<const short8v*>(&QP[w][mt * 16 + lr][lg * 8]);
  bh* plp = &QP[w][0][0];
  f32x4 Oacc[4][2];
  float psum[4] = {0.f, 0.f, 0.f, 0.f};
#pragma unroll
  for (int mt = 0; mt < 4; ++mt) { Oacc[mt][0] = z4; Oacc[mt][1] = z4; }
#pragma unroll
  for (int kt = 0; kt < 4; ++kt) {
    short8v bvf[2][2];
#pragma unroll
    for (int dt = 0; dt < 2; ++dt)
#pragma unroll
      for (int ks = 0; ks < 2; ++ks)
        bvf[dt][ks] = *reinterpret_cast<const short8v*>(&Vt[dt * 16 + lr][kt * 64 + ks * 32 + lg * 8]);
#pragma unroll
    for (int mt = 0; mt < 4; ++mt) {
      f32x4 st[4];
#pragma unroll
      for (int nt = 0; nt < 4; ++nt) {
        short8v bk = *reinterpret_cast<const short8v*>(&Ks[kt * 64 + nt * 16 + lr][lg * 8]);
        st[nt] = MFMA16(bk, aq[mt], z4);
      }
      float ps = 0.f;
#pragma unroll
      for (int nt = 0; nt < 4; ++nt) {
        float p0 = exp2f(st[nt][0]);
        float p1 = exp2f(st[nt][1]);
        float p2 = exp2f(st[nt][2]);
        float p3 = exp2f(st[nt][3]);
        ps += (p0 + p1) + (p2 + p3);
        short4v pk;
        pk[0] = bh_bits(p0); pk[1] = bh_bits(p1); pk[2] = bh_bits(p2); pk[3] = bh_bits(p3);
        *reinterpret_cast<short4v*>(&plp[lr * 72 + nt * 16 + 4 * lg]) = pk;
      }
      psum[mt] += ps;
#pragma unroll
      for (int ks = 0; ks < 2; ++ks) {
        short8v ap = *reinterpret_cast<const short8v*>(&plp[lr * 72 + ks * 32 + lg * 8]);
        Oacc[mt][0] = MFMA16(ap, bvf[0][ks], Oacc[mt][0]);
        Oacc[mt][1] = MFMA16(ap, bvf[1][ks], Oacc[mt][1]);
      }
    }
  }
#pragma unroll
  for (int mt = 0; mt < 4; ++mt) {
    float ps = psum[mt];
    ps += __shfl_xor(ps, 16, 64);
    ps += __shfl_xor(ps, 32, 64);
    float inv = 1.f / ps;
#pragma unroll
    for (int r = 0; r < 4; ++r) {
      float invr = __shfl(inv, 4 * lg + r, 64);
      long row = R0 + w * 64 + mt * 16 + 4 * lg + r;
      O[row * 128 + ch + lr]      = __float2bfloat16(Oacc[mt][0][r] * invr);
      O[row * 128 + ch + 16 + lr] = __float2bfloat16(Oacc[mt][1][r] * invr);
    }
  }
}

// ---------------------------------------------------------------------------
// conv (r16 form, ph chain removed): bounds-checked loads, 1024 blocks, ReLU,
// writes y_h in raw-.view() flat layout with wide stores.
// ---------------------------------------------------------------------------
__global__ __launch_bounds__(256) void sf_convy(const bh* __restrict__ Xh,
                                                const bh* __restrict__ Wr,
                                                const float* __restrict__ cbias,
                                                bh* __restrict__ Yh) {
  __shared__ bh Lw[4][32][140];
  const int t = threadIdx.x, lane = t & 63, w = t >> 6;
  const int lr = lane & 15, lg = lane >> 4;
  const int bnc = blockIdx.x >> 1;
  const int half = blockIdx.x & 1;
  const int b = bnc >> 7, stk = bnc & 127;
  const int R0 = half * 128 + w * 32;
  const f32x4 z4 = {0.f, 0.f, 0.f, 0.f};
  const short8v zf = {0, 0, 0, 0, 0, 0, 0, 0};
  f32x4 acc[2][8];
#pragma unroll
  for (int m = 0; m < 2; ++m)
#pragma unroll
    for (int n = 0; n < 8; ++n) acc[m][n] = z4;
#pragma unroll
  for (int tap = 0; tap < 3; ++tap) {
    const int shift = 2 * tap - 2;
#pragma unroll
    for (int ks = 0; ks < 4; ++ks) {
      int s0 = R0 + lr + shift;
      int s1 = s0 + 16;
      short8v a0 = zf, a1 = zf;
      if ((unsigned)s0 < 256u)
        a0 = *reinterpret_cast<const short8v*>(Xh + ((long)bnc * 256 + s0) * 128 + ks * 32 + lg * 8);
      if ((unsigned)s1 < 256u)
        a1 = *reinterpret_cast<const short8v*>(Xh + ((long)bnc * 256 + s1) * 128 + ks * 32 + lg * 8);
#pragma unroll
      for (int n = 0; n < 8; ++n) {
        short8v bb = *reinterpret_cast<const short8v*>(Wr + (long)tap * 16384 + (long)(n * 16 + lr) * 128 + ks * 32 + lg * 8);
        acc[0][n] = MFMA16(a0, bb, acc[0][n]);
        acc[1][n] = MFMA16(a1, bb, acc[1][n]);
      }
    }
  }
#pragma unroll
  for (int n = 0; n < 8; ++n) {
    float bv = cbias[n * 16 + lr];
#pragma unroll
    for (int m = 0; m < 2; ++m)
#pragma unroll
      for (int r = 0; r < 4; ++r)
        Lw[w][m * 16 + 4 * lg + r][n * 16 + lr] = __float2bfloat16(fmaxf(acc[m][n][r] + bv, 0.f));
  }
#pragma unroll
  for (int c = 0; c < 8; ++c) {
    int row_l = c * 4 + lg;
    int sc = R0 + row_l;
    int rp = b * 128 + (sc >> 1);
    int sp = ((sc & 1) << 7) + stk;
    short8v v = *reinterpret_cast<const short8v*>(&Lw[w][row_l][lr * 8]);
    *reinterpret_cast<short8v*>(Yh + ((long)rp * 256 + sp) * 128 + lr * 8) = v;
  }
}

// ---------------------------------------------------------------------------
// encdec v11: X -> (Wo) y_l [stored] -> (pl2) y_l2 -> heads. (q_l eliminated)
// ---------------------------------------------------------------------------
__global__ __launch_bounds__(256) void sf_encdec(const bh* __restrict__ X,
                                                 const bh* __restrict__ Wo, const float* __restrict__ bo,
                                                 const bh* __restrict__ Wpl2, const float* __restrict__ bpl2,
                                                 const float* __restrict__ rw, const float* __restrict__ rb,
                                                 const float* __restrict__ cw, const float* __restrict__ cb,
                                                 bh* __restrict__ Yl, float* __restrict__ out,
                                                 long off_reg, long off_cla) {
  __shared__ bh Lw[4][32][140];
  __shared__ float hw[3][128];
  const int t = threadIdx.x, lane = t & 63, w = t >> 6;
  const int lr = lane & 15, lg = lane >> 4;
  const long R0 = (long)blockIdx.x * 128 + w * 32;
  const f32x4 z4 = {0.f, 0.f, 0.f, 0.f};
  if (t < 128) { hw[0][t] = rw[t]; hw[1][t] = cw[t]; hw[2][t] = cw[128 + t]; }
  // ---- stage A: y_l = X·Wo^T + bo, stored ----
  {
    short8v a[2][4];
#pragma unroll
    for (int ks = 0; ks < 4; ++ks) {
      a[0][ks] = *reinterpret_cast<const short8v*>(X + (R0 + lr) * 128 + ks * 32 + lg * 8);
      a[1][ks] = *reinterpret_cast<const short8v*>(X + (R0 + 16 + lr) * 128 + ks * 32 + lg * 8);
    }
    f32x4 acc[2][8];
#pragma unroll
    for (int m = 0; m < 2; ++m)
#pragma unroll
      for (int n = 0; n < 8; ++n) acc[m][n] = z4;
#pragma unroll
    for (int ks = 0; ks < 4; ++ks)
#pragma unroll
      for (int n = 0; n < 8; ++n) {
        short8v b = *reinterpret_cast<const short8v*>(Wo + (long)(n * 16 + lr) * 128 + ks * 32 + lg * 8);
        acc[0][n] = MFMA16(a[0][ks], b, acc[0][n]);
        acc[1][n] = MFMA16(a[1][ks], b, acc[1][n]);
      }
#pragma unroll
    for (int n = 0; n < 8; ++n) {
      float bv = bo[n * 16 + lr];
#pragma unroll
      for (int m = 0; m < 2; ++m)
#pragma unroll
        for (int r = 0; r < 4; ++r)
          Lw[w][m * 16 + 4 * lg + r][n * 16 + lr] = __float2bfloat16(acc[m][n][r] + bv);
    }
#pragma unroll
    for (int c = 0; c < 8; ++c) {
      int row_l = c * 4 + lg;
      short8v v = *reinterpret_cast<const short8v*>(&Lw[w][row_l][lr * 8]);
      *reinterpret_cast<short8v*>(Yl + (R0 + row_l) * 128 + lr * 8) = v;
    }
  }
  // ---- stage C: y_l2 = y_l·pl2^T + bpl2 ----
  {
    short8v a[2][4];
#pragma unroll
    for (int ks = 0; ks < 4; ++ks) {
      a[0][ks] = *reinterpret_cast<const short8v*>(&Lw[w][lr][ks * 32 + lg * 8]);
      a[1][ks] = *reinterpret_cast<const short8v*>(&Lw[w][16 + lr][ks * 32 + lg * 8]);
    }
    f32x4 acc[2][8];
#pragma unroll
    for (int m = 0; m < 2; ++m)
#pragma unroll
      for (int n = 0; n < 8; ++n) acc[m][n] = z4;
#pragma unroll
    for (int ks = 0; ks < 4; ++ks)
#pragma unroll
      for (int n = 0; n < 8; ++n) {
        short8v b = *reinterpret_cast<const short8v*>(Wpl2 + (long)(n * 16 + lr) * 128 + ks * 32 + lg * 8);
        acc[0][n] = MFMA16(a[0][ks], b, acc[0][n]);
        acc[1][n] = MFMA16(a[1][ks], b, acc[1][n]);
      }
#pragma unroll
    for (int n = 0; n < 8; ++n) {
      float bv = bpl2[n * 16 + lr];
#pragma unroll
      for (int m = 0; m < 2; ++m)
#pragma unroll
        for (int r = 0; r < 4; ++r)
          Lw[w][m * 16 + 4 * lg + r][n * 16 + lr] = __float2bfloat16(acc[m][n][r] + bv);
    }
  }
  __syncthreads();
  // ---- heads on y_l2 tile ----
  {
    const int rr = lane >> 1, hh = lane & 1;
    float d0 = 0.f, d1 = 0.f, d2 = 0.f;
#pragma unroll
    for (int j = 0; j < 8; ++j) {
      short8v v8 = *reinterpret_cast<const short8v*>(&Lw[w][rr][hh * 64 + j * 8]);
      const bh* vv = reinterpret_cast<const bh*>(&v8);
#pragma unroll
      for (int k = 0; k < 8; ++k) {
        float f = __bfloat162float(vv[k]);
        int c = hh * 64 + j * 8 + k;
        d0 = fmaf(f, hw[0][c], d0);
        d1 = fmaf(f, hw[1][c], d1);
        d2 = fmaf(f, hw[2][c], d2);
      }
    }
    d0 += __shfl_xor(d0, 1, 64);
    d1 += __shfl_xor(d1, 1, 64);
    d2 += __shfl_xor(d2, 1, 64);
    if (hh == 0) {
      long row = R0 + rr;
      d0 += rb[0]; d1 += cb[0]; d2 += cb[1];
      float mx = fmaxf(d1, d2);
      float e1 = __expf(d1 - mx), e2 = __expf(d2 - mx);
      float inv = 1.f / (e1 + e2);
      out[off_reg + row] = d0;
      out[off_cla + row * 2] = e1 * inv;
      out[off_cla + row * 2 + 1] = e2 * inv;
    }
  }
}

// ---------------------------------------------------------------------------
// Final (r16-verbatim): fused = self·Was + cross·Wac + biases (f32) -> heads.
// ---------------------------------------------------------------------------
__global__ __launch_bounds__(256) void sf_fin2(const bh* __restrict__ Xs,
                                               const bh* __restrict__ Was, const float* __restrict__ bs,
                                               const bh* __restrict__ Xc,
                                               const bh* __restrict__ Wac, const float* __restrict__ bc,
                                               const float* __restrict__ rw, const float* __restrict__ rb,
                                               const float* __restrict__ cw, const float* __restrict__ cb,
                                               float* __restrict__ out, long off_reg, long off_cla) {
  __shared__ bh Lw[4][32][140];
  __shared__ float hw[3][128];
  const int t = threadIdx.x, lane = t & 63, w = t >> 6;
  const int lr = lane & 15, lg = lane >> 4;
  const long R0 = (long)blockIdx.x * 128 + w * 32;
  const f32x4 z4 = {0.f, 0.f, 0.f, 0.f};
  if (t < 128) { hw[0][t] = rw[t]; hw[1][t] = cw[t]; hw[2][t] = cw[128 + t]; }
  {
    f32x4 acc[2][8];
#pragma unroll
    for (int m = 0; m < 2; ++m)
#pragma unroll
      for (int n = 0; n < 8; ++n) acc[m][n] = z4;
    {
      short8v a[2][4];
#pragma unroll
      for (int ks = 0; ks < 4; ++ks) {
        a[0][ks] = *reinterpret_cast<const short8v*>(Xs + (R0 + lr) * 128 + ks * 32 + lg * 8);
        a[1][ks] = *reinterpret_cast<const short8v*>(Xs + (R0 + 16 + lr) * 128 + ks * 32 + lg * 8);
      }
#pragma unroll
      for (int ks = 0; ks < 4; ++ks)
#pragma unroll
        for (int n = 0; n < 8; ++n) {
          short8v b = *reinterpret_cast<const short8v*>(Was + (long)(n * 16 + lr) * 128 + ks * 32 + lg * 8);
          acc[0][n] = MFMA16(a[0][ks], b, acc[0][n]);
          acc[1][n] = MFMA16(a[1][ks], b, acc[1][n]);
        }
    }
    {
      short8v a[2][4];
#pragma unroll
      for (int ks = 0; ks < 4; ++ks) {
        a[0][ks] = *reinterpret_cast<const short8v*>(Xc + (R0 + lr) * 128 + ks * 32 + lg * 8);
        a[1][ks] = *reinterpret_cast<const short8v*>(Xc + (R0 + 16 + lr) * 128 + ks * 32 + lg * 8);
      }
#pragma unroll
      for (int ks = 0; ks < 4; ++ks)
#pragma unroll
        for (int n = 0; n < 8; ++n) {
          short8v b = *reinterpret_cast<const short8v*>(Wac + (long)(n * 16 + lr) * 128 + ks * 32 + lg * 8);
          acc[0][n] = MFMA16(a[0][ks], b, acc[0][n]);
          acc[1][n] = MFMA16(a[1][ks], b, acc[1][n]);
        }
    }
#pragma unroll
    for (int n = 0; n < 8; ++n) {
      float bv = bs[n * 16 + lr] + bc[n * 16 + lr];
#pragma unroll
      for (int m = 0; m < 2; ++m)
#pragma unroll
        for (int r = 0; r < 4; ++r)
          Lw[w][m * 16 + 4 * lg + r][n * 16 + lr] = __float2bfloat16(acc[m][n][r] + bv);
    }
  }
  __syncthreads();
  {
    const int rr = lane >> 1, hh = lane & 1;
    float d0 = 0.f, d1 = 0.f, d2 = 0.f;
#pragma unroll
    for (int j = 0; j < 8; ++j) {
      short8v v8 = *reinterpret_cast<const short8v*>(&Lw[w][rr][hh * 64 + j * 8]);
      const bh* vv = reinterpret_cast<const bh*>(&v8);
#pragma unroll
      for (int k = 0; k < 8; ++k) {
        float f = __bfloat162float(vv[k]);
        int c = hh * 64 + j * 8 + k;
        d0 = fmaf(f, hw[0][c], d0);
        d1 = fmaf(f, hw[1][c], d1);
        d2 = fmaf(f, hw[2][c], d2);
      }
    }
    d0 += __shfl_xor(d0, 1, 64);
    d1 += __shfl_xor(d1, 1, 64);
    d2 += __shfl_xor(d2, 1, 64);
    if (hh == 0) {
      long row = R0 + rr;
      d0 += rb[0]; d1 += cb[0]; d2 += cb[1];
      float mx = fmaxf(d1, d2);
      float e1 = __expf(d1 - mx), e2 = __expf(d2 - mx);
      float inv = 1.f / (e1 + e2);
      out[off_reg + row] = d0;
      out[off_cla + row * 2] = e1 * inv;
      out[off_cla + row * 2 + 1] = e2 * inv;
    }
  }
}

// ---------------------------------------------------------------------------
extern "C" void kernel_launch(void* const* d_in, const int* in_sizes, int n_in,
                              void* d_out, int out_size, void* d_ws, size_t ws_size,
                              hipStream_t stream) {
  (void)in_sizes; (void)n_in; (void)out_size; (void)ws_size;
  const float* x       = (const float*)d_in[0];
  const float* ta_w_in = (const float*)d_in[2];
  const float* ta_b_in = (const float*)d_in[3];
  const float* ta_w_o  = (const float*)d_in[4];
  const float* ta_b_o  = (const float*)d_in[5];
  const float* conv_w  = (const float*)d_in[6];
  const float* conv_b  = (const float*)d_in[7];
  const float* pl_w    = (const float*)d_in[8];
  const float* pl_b    = (const float*)d_in[9];
  const float* ph_w    = (const float*)d_in[10];
  const float* ph_b    = (const float*)d_in[11];
  const float* as_w_in = (const float*)d_in[12];
  const float* as_b_in = (const float*)d_in[13];
  const float* as_w_o  = (const float*)d_in[14];
  const float* as_b_o  = (const float*)d_in[15];
  const float* ac_w_in = (const float*)d_in[16];
  const float* ac_b_in = (const float*)d_in[17];
  const float* ac_w_o  = (const float*)d_in[18];
  const float* ac_b_o  = (const float*)d_in[19];
  const float* rl_w    = (const float*)d_in[20];
  const float* rl_b    = (const float*)d_in[21];
  const float* cl_w    = (const float*)d_in[22];
  const float* cl_b    = (const float*)d_in[23];
  const float* rf_w    = (const float*)d_in[24];
  const float* rf_b    = (const float*)d_in[25];
  const float* cf_w    = (const float*)d_in[26];
  const float* cf_b    = (const float*)d_in[27];
  float* out = (float*)d_out;

  bh* S0 = (bh*)d_ws;
  bh* S1 = S0 + SF_ELEMS;
  bh* S2 = S1 + SF_ELEMS;
  bh* S3 = S2 + SF_ELEMS;
  bh* S4 = S3 + SF_ELEMS;
  bh* A  = S4 + SF_ELEMS;             // bf16 arena (425984)
  float* PE = (float*)(A + 425984);   // 32768 f32
  float* FB = PE + 32768;             // 896 f32 folded biases

  dim3 blk(256);
  const int GZ = (int)(SF_ELEMS / 256);
  const int GL = 1024;

  sf_wcvt<<<1216, blk, 0, stream>>>(ta_w_in, ta_w_o, pl_w, ph_w, ac_w_in, ac_w_o,
                                    as_w_in, as_w_o, conv_w, A);
  sf_pe<<<128, blk, 0, stream>>>(PE);
  sf_foldb<<<4, blk, 0, stream>>>(as_w_in, as_b_in, ac_w_in, ac_b_in,
                                  pl_w, pl_b, ph_b, FB);
  sf_foldw<<<7, blk, 0, stream>>>(A);

  // ---- encoder ----
  sf_buildzx<<<GZ, blk, 0, stream>>>(x, PE, S0, S3);                           // S0 = z, S3 = xh
  sf_attnp<<<2048, blk, 0, stream>>>(S0, S0, A, ta_b_in, S1);                  // S1 = enc attn
  sf_encdec<<<GL, blk, 0, stream>>>(S1, A + 49152, ta_b_o, A + 409600, FB + 768,
                                    rl_w, rl_b, cl_w, cl_b, S2, out,
                                    393216L, 524288L);                         // S2 = y_l + lreg/lcla
  sf_convy<<<1024, blk, 0, stream>>>(S3, A + 229376, conv_b, S4);              // S4 = y_h

  // ---- cross attention (Q from y_l via Wq·pl; K/V from y_h via Wkv·ph) ----
  sf_attnp<<<2048, blk, 0, stream>>>(S2, S4, A + 360448, FB + 384, S3);        // S3 = cross attn

  // ---- self attention (Q/K/V from y_l via as·pl) ----
  sf_attnp<<<2048, blk, 0, stream>>>(S2, S2, A + 311296, FB, S1);              // S1 = self attn

  // ---- fused out-projections + heads ----
  sf_fin2<<<GL, blk, 0, stream>>>(S1, A + 212992, as_b_o, S3, A + 147456, ac_b_o,
                                  rf_w, rf_b, cf_w, cf_b, out, 0L, 131072L);   // reg/cla
}